// Round 11
// baseline (339.430 us; speedup 1.0000x reference)
//
#include <hip/hip_runtime.h>
#include <hip/hip_bf16.h>
#include <stdint.h>
#include <stddef.h>

#define NEG_SLOPE 0.2f
#define XS 136   // padded LDS row stride in bf16 elems (272 B, 16B-aligned, kills 256B bank alias)

// CSR bucket build: bucket = dst >> 9 (512 nodes/bucket), 196 buckets for N=100k.
#define NBK   196
#define BWSH  9
#define BCAP  12288
#define NPREP 64   // prep blocks appended after scatter blocks
#define W2S   34   // w2 LDS stride (ushorts) to spread banks

typedef __bf16 bf16x8 __attribute__((ext_vector_type(8)));
typedef float  f32x4  __attribute__((ext_vector_type(4)));

__device__ __forceinline__ float bf2f(__hip_bfloat16 b){ return __bfloat162float(b); }
__device__ __forceinline__ float lo_bf(unsigned u){ return __uint_as_float(u << 16); }
__device__ __forceinline__ float hi_bf(unsigned u){ return __uint_as_float(u & 0xffff0000u); }
__device__ __forceinline__ float lrelu(float u){ return fmaxf(u, NEG_SLOPE * u); }
__device__ __forceinline__ unsigned short f2bf(float f){           // RNE bf16
    unsigned u = __float_as_uint(f);
    return (unsigned short)((u + 0x7fffu + ((u >> 16) & 1u)) >> 16);
}
__device__ __forceinline__ float bfs2f(unsigned short s){ return __uint_as_float((unsigned)s << 16); }
__device__ __forceinline__ float ldraw(const void* p, int i, int isf){
    return isf ? ((const float*)p)[i] : bf2f(((const __hip_bfloat16*)p)[i]);
}

// ---------------------------------------------------------------- prep ∥ bucket scatter
// Blocks [0, nsb): register-resident bucket scatter (self-detects int64 via ballot).
// Blocks [nsb, nsb+NPREP): weight prep from RAW inputs (self-detects fp32 via vote);
//   block nsb publishes flags[1] for downstream kernels.
//   w1x: rows 0-127 = W1^T; 128+h/136+h = va1s hi/lo; 144+h/152+h = va1d hi/lo
//   w2x: rows 0-31 = W2^T; 32/33 = va2s hi/lo; 34/35 = va2d hi/lo; 36-47 zero
// gcur: pre-zeroed by memset; stores per-bucket COUNTS (base = b*BCAP + old).
#define WTS_TOTAL 20993
__global__ __launch_bounds__(256) void prep_scatter_kernel(
        const void* __restrict__ ei, const unsigned* __restrict__ xw,
        int* __restrict__ flags,
        int* __restrict__ gcur, unsigned* __restrict__ pairs, int E, int Et, int nsb,
        const void* W1, const void* W2, const void* a1s, const void* a1d,
        const void* b1, const void* a2s, const void* a2d, const void* b2,
        const void* Wh, const void* bh,
        float* __restrict__ w, unsigned short* __restrict__ w1x,
        unsigned short* __restrict__ w2x){
    const int t = threadIdx.x;
    if ((int)blockIdx.x < nsb){
        // ---------------- scatter ----------------
        __shared__ int cnt[NBK], base[NBK], lcnt[NBK];
        __shared__ int s64;
        if (t < 64){
            unsigned long long m = __ballot(((const unsigned*)ei)[2*t + 1] != 0u);
            if (t == 0) s64 = (m == 0ull) ? 1 : 0;
        }
        const int e0 = blockIdx.x * 4096;
        const int nE = min(4096, Et - e0);
        for (int i = t; i < NBK; i += 256){ cnt[i] = 0; lcnt[i] = 0; }
        __syncthreads();
        const int is64 = s64;
        int2 sd[16];
#pragma unroll
        for (int k = 0; k < 16; k++){
            int j = t + k * 256;
            if (j < nE){
                int e = e0 + j, s, d;
                if (e >= E){ s = e - E; d = s; }
                else if (is64){
                    const long long* p = (const long long*)ei;
                    s = (int)p[e]; d = (int)p[(size_t)E + e];
                } else {
                    const int* p = (const int*)ei;
                    s = p[e]; d = p[(size_t)E + e];
                }
                sd[k] = make_int2(s, d);
                atomicAdd(&cnt[d >> BWSH], 1);
            } else sd[k].y = -1;
        }
        __syncthreads();
        for (int b = t; b < NBK; b += 256)
            base[b] = cnt[b] ? (b * BCAP + atomicAdd(&gcur[b], cnt[b])) : 0;
        __syncthreads();
#pragma unroll
        for (int k = 0; k < 16; k++){
            if (sd[k].y >= 0){
                int b = sd[k].y >> BWSH;
                int r = atomicAdd(&lcnt[b], 1);
                pairs[(size_t)base[b] + r] = ((unsigned)sd[k].x << BWSH) | (unsigned)(sd[k].y & 511);
            }
        }
    } else {
        // ---------------- prep (grid-stride over NPREP blocks) ----------------
        __shared__ int vote;
        __shared__ int sflag;
        if (t == 0) vote = 0;
        __syncthreads();
        {
            unsigned lo = xw[t] & 0xffffu;
            unsigned e  = (lo >> 7) & 0xffu;
            int pl = ((lo & 0x7fffu) == 0u || (e >= 100u && e <= 140u)) ? 1 : 0;
            atomicAdd(&vote, pl);
        }
        __syncthreads();
        if (t == 0){
            sflag = (vote < 128) ? 1 : 0;
            if ((int)blockIdx.x == nsb){ flags[0] = 0; flags[1] = sflag; }
        }
        __syncthreads();
        const int isf = sflag;
        const int p   = blockIdx.x - nsb;
        const int tid = p * 256 + t;
        const int NT  = NPREP * 256;
        // wts tail: indices 20480..20992 (attn vecs + biases)
        for (int i = tid; i < 513; i += NT){
            int gi = 20480 + i;
            const void* src; int off;
            if      (gi < 20608){ src = a1s; off = gi - 20480; }
            else if (gi < 20736){ src = a1d; off = gi - 20608; }
            else if (gi < 20864){ src = b1;  off = gi - 20736; }
            else if (gi < 20896){ src = a2s; off = gi - 20864; }
            else if (gi < 20928){ src = a2d; off = gi - 20896; }
            else if (gi < 20960){ src = b2;  off = gi - 20928; }
            else if (gi < 20992){ src = Wh;  off = gi - 20960; }
            else                { src = bh;  off = 0; }
            w[gi] = ldraw(src, off, isf);
        }
        // W2 natural fp32 (for gather1's fused matvec)
        for (int i = tid; i < 4096; i += NT)
            w[16384 + i] = ldraw(W2, i, isf);
        // W1^T bf16
        for (int i = tid; i < 16384; i += NT){
            int c = i >> 7, k = i & 127;
            w1x[i] = f2bf(ldraw(W1, k*128 + c, isf));
        }
        // fused logit vectors layer 1 (from raw inputs)
        for (int i = tid; i < 1024; i += NT){          // i = h*128 + k
            int h = i >> 7, k = i & 127;
            float ss = 0.f, dd = 0.f;
#pragma unroll
            for (int j = 0; j < 16; j++){
                float hv = ldraw(W1, k*128 + h*16 + j, isf);
                ss += hv * ldraw(a1s, h*16 + j, isf);
                dd += hv * ldraw(a1d, h*16 + j, isf);
            }
            unsigned short sh = f2bf(ss), dh = f2bf(dd);
            w1x[(128+h)*128 + k] = sh;
            w1x[(136+h)*128 + k] = f2bf(ss - bfs2f(sh));
            w1x[(144+h)*128 + k] = dh;
            w1x[(152+h)*128 + k] = f2bf(dd - bfs2f(dh));
        }
    }
}

// ---------------------------------------------------------------- csr_build ∥ GEMM1
// Blocks [0, NBK): per-bucket CSR build. Blocks [NBK, ...): MFMA GEMM1 + attn1.
__global__ __launch_bounds__(256) void g1csr_kernel(
        const unsigned* __restrict__ pairs, const int* __restrict__ gcur,
        int* __restrict__ rowptr, int* __restrict__ csr_src, int Nn,
        const void* __restrict__ xv, const unsigned short* __restrict__ w1x,
        const int* __restrict__ flags, __hip_bfloat16* __restrict__ h1b,
        float* __restrict__ as1, float* __restrict__ ad1){
    __shared__ __align__(16) char smem[52224];
    const int t = threadIdx.x;
    if ((int)blockIdx.x < NBK){
        // ---------------- csr_build ----------------
        int* ssz   = (int*)smem;           // 256
        int* sscan = ssz + 256;            // 256
        int* cnt   = sscan + 256;          // 512
        int* sh    = cnt + 512;            // 256
        const int b = blockIdx.x;
        int v = (t < NBK) ? gcur[t] : 0;   // counts
        ssz[t] = v; sscan[t] = v;
        __syncthreads();
        for (int off = 1; off < 256; off <<= 1){
            int x = (t >= off) ? sscan[t - off] : 0;
            __syncthreads();
            sscan[t] += x;
            __syncthreads();
        }
        const int sz = ssz[b];
        const int eb = (b == 0) ? 0 : sscan[b - 1];
        if (b == 0 && t == 0) rowptr[Nn] = sscan[NBK - 1];
        const unsigned* pp = pairs + (size_t)b * BCAP;
        cnt[t] = 0; cnt[t + 256] = 0;
        __syncthreads();
        for (int i = t; i < sz; i += 256) atomicAdd(&cnt[pp[i] & 511u], 1);
        __syncthreads();
        int l0 = 2*t, l1 = 2*t + 1;
        int s0 = cnt[l0], s1 = cnt[l1], ts = s0 + s1;
        sh[t] = ts; __syncthreads();
        for (int off = 1; off < 256; off <<= 1){
            int x = (t >= off) ? sh[t - off] : 0;
            __syncthreads();
            sh[t] += x;
            __syncthreads();
        }
        int excl = sh[t] - ts;
        __syncthreads();
        cnt[l0] = eb + excl;
        cnt[l1] = eb + excl + s0;
        int n0 = (b << BWSH) + l0, n1 = (b << BWSH) + l1;
        if (n0 < Nn) rowptr[n0] = cnt[l0];
        if (n1 < Nn) rowptr[n1] = cnt[l1];
        __syncthreads();
        for (int i = t; i < sz; i += 256){
            unsigned sd = pp[i];
            int pos = atomicAdd(&cnt[sd & 511u], 1);
            csr_src[pos] = (int)(sd >> BWSH);
        }
    } else {
        // ---------------- gemm1 (MFMA) + attn1 ----------------
        __bf16* xls = (__bf16*)smem;                    // 64*XS = 17408 B
        __bf16* wls = (__bf16*)(smem + 64 * XS * 2);    // 128*XS = 34816 B
        const int row0 = ((int)blockIdx.x - NBK) * 64;
        const int n = Nn;

#pragma unroll
        for (int k = 0; k < 8; k++){
            int e = (t + k * 256) * 8;
            int c = e >> 7, kk = e & 127;
            *(uint4*)(&wls[c * XS + kk]) = *(const uint4*)(w1x + e);
        }
        if (row0 + 64 <= n){
            if (flags[1]){                              // fp32, float4 loads
                const float* xp = (const float*)xv + (size_t)row0 * 128;
#pragma unroll
                for (int k = 0; k < 8; k++){
                    int e = (t + k * 256) * 4;
                    int row = e >> 7, col = e & 127;
                    float4 vv = *(const float4*)(xp + e);
                    uint2 o;
                    o.x = (unsigned)f2bf(vv.x) | ((unsigned)f2bf(vv.y) << 16);
                    o.y = (unsigned)f2bf(vv.z) | ((unsigned)f2bf(vv.w) << 16);
                    *(uint2*)(&xls[row * XS + col]) = o;
                }
            } else {                                    // bf16, uint4 loads
                const unsigned short* xp = (const unsigned short*)xv + (size_t)row0 * 128;
#pragma unroll
                for (int k = 0; k < 4; k++){
                    int e = (t + k * 256) * 8;
                    int row = e >> 7, col = e & 127;
                    *(uint4*)(&xls[row * XS + col]) = *(const uint4*)(xp + e);
                }
            }
        } else {
            const int limit = (n - row0) * 128;
            if (flags[1]){
                const float* xp = (const float*)xv + (size_t)row0 * 128;
                for (int i = t; i < 64 * 128; i += 256){
                    float v = (i < limit) ? xp[i] : 0.f;
                    xls[(i >> 7) * XS + (i & 127)] = (__bf16)v;
                }
            } else {
                const unsigned short* xp = (const unsigned short*)xv + (size_t)row0 * 128;
                for (int i = t; i < 64 * 128; i += 256){
                    unsigned short v = (i < limit) ? xp[i] : (unsigned short)0;
                    ((unsigned short*)xls)[(i >> 7) * XS + (i & 127)] = v;
                }
            }
        }
        __syncthreads();

        const int w    = t >> 6;
        const int lane = t & 63;
        const int l15  = lane & 15;
        const int quad = lane >> 4;

        f32x4 acc[8] = {};
        f32x4 accS = {}, accD = {};
        const __bf16* xbase = &xls[(w * 16 + l15) * XS + quad * 8];
        const __bf16* wbase = &wls[l15 * XS + quad * 8];
        const unsigned short* vsrow = w1x + (128 + l15) * 128 + quad * 8;
        const unsigned short* vdrow = w1x + (144 + l15) * 128 + quad * 8;

#pragma unroll
        for (int ks = 0; ks < 4; ks++){
            bf16x8 af = *(const bf16x8*)(xbase + ks * 32);
#pragma unroll
            for (int tt = 0; tt < 8; tt++){
                bf16x8 bfr = *(const bf16x8*)(wbase + tt * 16 * XS + ks * 32);
                acc[tt] = __builtin_amdgcn_mfma_f32_16x16x32_bf16(af, bfr, acc[tt], 0, 0, 0);
            }
            bf16x8 bS = *(const bf16x8*)(vsrow + ks * 32);
            bf16x8 bD = *(const bf16x8*)(vdrow + ks * 32);
            accS = __builtin_amdgcn_mfma_f32_16x16x32_bf16(af, bS, accS, 0, 0, 0);
            accD = __builtin_amdgcn_mfma_f32_16x16x32_bf16(af, bD, accD, 0, 0, 0);
        }

#pragma unroll
        for (int tt = 0; tt < 8; tt++){
            int col = tt * 16 + l15;
#pragma unroll
            for (int r = 0; r < 4; r++){
                int row = row0 + w * 16 + quad * 4 + r;
                if (row < n) h1b[(size_t)row * 128 + col] = __float2bfloat16(acc[tt][r]);
            }
        }
#pragma unroll
        for (int r = 0; r < 4; r++){
            float vs = accS[r] + __shfl_xor(accS[r], 8);   // hi + lo
            float vd = accD[r] + __shfl_xor(accD[r], 8);
            int row = row0 + w * 16 + quad * 4 + r;
            if (l15 < 8 && row < n){
                as1[(size_t)row * 8 + l15] = vs;
                ad1[(size_t)row * 8 + l15] = vd;
            }
        }
    }
}

// ---------------------------------------------------------------- gather L1 + GEMM2 + attn2
// One wave per dst node, 4 edges in flight, 16 lanes/edge, 8 ch/lane (uint4).
// Epilogue: out1 row (bias+ELU, fp32) -> wave-local LDS -> 128x32 matvec with
// W2 (bf16 LDS, [k][c] stride W2S) -> h2b bf16 + exact attn2 logits.
__global__ __launch_bounds__(256) void gather1_kernel(const int* __restrict__ rowptr,
                                                      const int* __restrict__ csr_src,
                                                      const float* __restrict__ as1,
                                                      const float* __restrict__ ad1,
                                                      const unsigned* __restrict__ h1u,
                                                      const float* __restrict__ b1,
                                                      const float* __restrict__ W2f,
                                                      const float* __restrict__ a2blk,
                                                      __hip_bfloat16* __restrict__ h2b,
                                                      float* __restrict__ as2,
                                                      float* __restrict__ ad2, int n){
    __shared__ __align__(16) unsigned short w2ls[128 * W2S];  // 8704 B
    __shared__ float a2ls[64];                                 // a2s[32] | a2d[32]
    __shared__ __align__(16) float o1f[4 * 128];               // out1 rows per wave
    const int t = threadIdx.x;
    for (int i = t; i < 4096; i += 256){
        int k = i >> 5, c = i & 31;
        w2ls[k * W2S + c] = f2bf(W2f[i]);
    }
    if (t < 64) a2ls[t] = a2blk[t];
    __syncthreads();

    const int wv   = t >> 6;
    const int lane = t & 63;
    const int wid0 = blockIdx.x * 4 + wv;
    const bool active = wid0 < n;
    const int wid = active ? wid0 : 0;
    const int q    = lane >> 4;
    const int l15  = lane & 15;
    const int h    = l15 >> 1;
    const int start = active ? rowptr[wid] : 0;
    const int end   = active ? rowptr[wid + 1] : 0;
    const float adv = ad1[(size_t)wid * 8 + h];
    float den = 0.f;
    float num[8] = {0.f,0.f,0.f,0.f,0.f,0.f,0.f,0.f};
    for (int j = start + q; j < end; j += 4){
        int src = csr_src[j];
        float u = lrelu(as1[(size_t)src * 8 + h] + adv);
        float w = __expf(u);
        uint4 hv = *(const uint4*)(h1u + (size_t)src * 64 + (l15 << 2));
        den += w;
        num[0] += w * lo_bf(hv.x); num[1] += w * hi_bf(hv.x);
        num[2] += w * lo_bf(hv.y); num[3] += w * hi_bf(hv.y);
        num[4] += w * lo_bf(hv.z); num[5] += w * hi_bf(hv.z);
        num[6] += w * lo_bf(hv.w); num[7] += w * hi_bf(hv.w);
    }
    den += __shfl_xor(den, 16); den += __shfl_xor(den, 32);
#pragma unroll
    for (int k = 0; k < 8; k++){
        num[k] += __shfl_xor(num[k], 16);
        num[k] += __shfl_xor(num[k], 32);
    }
    // out1 row (bias + ELU) -> wave-local LDS (fp32)
    if (lane < 16){
        const int ch0 = l15 * 8;
        float inv = 1.f / (den + 1e-16f);
        float r[8];
#pragma unroll
        for (int k = 0; k < 8; k++){
            float v = num[k] * inv + b1[ch0 + k];
            r[k] = v > 0.f ? v : __expf(v) - 1.f;
        }
        float4* dst = (float4*)&o1f[wv * 128 + ch0];
        dst[0] = make_float4(r[0], r[1], r[2], r[3]);
        dst[1] = make_float4(r[4], r[5], r[6], r[7]);
    }
    // wave-synchronous: LDS write->read within one wave needs no barrier
    const int c    = lane & 31;
    const int half = lane >> 5;
    const float* o1p = &o1f[wv * 128 + half * 64];
    const unsigned short* wp = &w2ls[(half * 64) * W2S + c];
    float acc2 = 0.f;
#pragma unroll
    for (int j4 = 0; j4 < 16; j4++){
        float4 ov = *(const float4*)(o1p + j4 * 4);
        acc2 += ov.x * bfs2f(wp[(j4*4 + 0) * W2S]);
        acc2 += ov.y * bfs2f(wp[(j4*4 + 1) * W2S]);
        acc2 += ov.z * bfs2f(wp[(j4*4 + 2) * W2S]);
        acc2 += ov.w * bfs2f(wp[(j4*4 + 3) * W2S]);
    }
    acc2 += __shfl_xor(acc2, 32);                   // lanes now hold full h2[c]
    float vs = acc2 * a2ls[c];
    float vd = acc2 * a2ls[32 + c];
#pragma unroll
    for (int off = 1; off < 32; off <<= 1){
        vs += __shfl_xor(vs, off);
        vd += __shfl_xor(vd, off);
    }
    if (active){
        if (lane < 32) h2b[(size_t)wid * 32 + c] = __float2bfloat16(acc2);
        if (lane == 0){ as2[wid] = vs; ad2[wid] = vd; }
    }
}

// ---------------------------------------------------------------- gather L2 + head (fused)
// One wave per dst node, 4 edges in flight, 16 lanes/edge, 2 ch/lane.
__global__ __launch_bounds__(256) void gather2_kernel(const int* __restrict__ rowptr,
                                                      const int* __restrict__ csr_src,
                                                      const float* __restrict__ as2,
                                                      const float* __restrict__ ad2,
                                                      const unsigned* __restrict__ h2u,
                                                      const float* __restrict__ b2,
                                                      const float* __restrict__ Wh,
                                                      const float* __restrict__ bh,
                                                      const int* __restrict__ flags,
                                                      void* __restrict__ out, int n){
    int wid = blockIdx.x * 4 + (threadIdx.x >> 6);
    if (wid >= n) return;
    int lane = threadIdx.x & 63;
    int q    = lane >> 4;
    int i2   = lane & 15;
    int ch0  = i2 * 2;
    int start = rowptr[wid], end = rowptr[wid + 1];
    float adv = ad2[wid];
    float den = 0.f, num0 = 0.f, num1 = 0.f;
    for (int j = start + q; j < end; j += 4){
        int src = csr_src[j];
        float u = lrelu(as2[src] + adv);
        float w = __expf(u);
        unsigned hv = h2u[(size_t)src * 16 + i2];
        den += w;
        num0 += w * lo_bf(hv);
        num1 += w * hi_bf(hv);
    }
    den  += __shfl_xor(den, 16);  den  += __shfl_xor(den, 32);
    num0 += __shfl_xor(num0, 16); num0 += __shfl_xor(num0, 32);
    num1 += __shfl_xor(num1, 16); num1 += __shfl_xor(num1, 32);
    float inv = 1.f / (den + 1e-16f);
    float v0 = num0 * inv + b2[ch0];
    float v1 = num1 * inv + b2[ch0 + 1];
    v0 = v0 > 0.f ? v0 : __expf(v0) - 1.f;
    v1 = v1 > 0.f ? v1 : __expf(v1) - 1.f;
    float p = v0 * Wh[ch0] + v1 * Wh[ch0 + 1];
#pragma unroll
    for (int off = 1; off < 16; off <<= 1) p += __shfl_xor(p, off);
    if (lane == 0){
        float r = p + bh[0];
        if (flags[1]) ((float*)out)[wid] = r;
        else          ((__hip_bfloat16*)out)[wid] = __float2bfloat16(r);
    }
}

extern "C" void kernel_launch(void* const* d_in, const int* in_sizes, int n_in,
                              void* d_out, int out_size, void* d_ws, size_t ws_size,
                              hipStream_t stream){
    const void* x   = d_in[0];
    const void* ei  = d_in[1];

    const int Nn = in_sizes[0] / 128;     // 100000
    const int Ee = in_sizes[1] / 2;       // 1600000
    const int Et = Ee + Nn;               // 1700000
    const int nsb = (Et + 4095) / 4096;   // scatter blocks

    char* ws = (char*)d_ws;
    auto al = [](size_t v){ return (v + 255) & ~(size_t)255; };
    size_t off = 0;
    int*      flags  = (int*)(ws + off);      off = al(off + 16);
    float*    wts    = (float*)(ws + off);    off = al(off + (size_t)WTS_TOTAL * 4);
    unsigned short* w1x = (unsigned short*)(ws + off); off = al(off + 160 * 128 * 2);
    int*      gcur   = (int*)(ws + off);      off = al(off + (size_t)NBK * 4);
    int*      rowptr = (int*)(ws + off);      off = al(off + (size_t)(Nn + 1) * 4);
    int*      csrs   = (int*)(ws + off);      off = al(off + (size_t)Et * 4);
    unsigned* pairs  = (unsigned*)(ws + off); off = al(off + (size_t)NBK * BCAP * 4);
    __hip_bfloat16* h1b = (__hip_bfloat16*)(ws + off); off = al(off + (size_t)Nn * 128 * 2);
    float* as1  = (float*)(ws + off); off = al(off + (size_t)Nn * 8 * 4);
    float* ad1  = (float*)(ws + off); off = al(off + (size_t)Nn * 8 * 4);
    __hip_bfloat16* h2b = (__hip_bfloat16*)(ws + off); off = al(off + (size_t)Nn * 32 * 2);
    float* as2  = (float*)(ws + off); off = al(off + (size_t)Nn * 4);
    float* ad2  = (float*)(ws + off); off = al(off + (size_t)Nn * 4);

    float* W2f  = wts + 16384;
    float* b1f  = wts + 20736;
    float* a2blk= wts + 20864;   // a2s[32] then a2d[32], contiguous
    float* b2f  = wts + 20928;
    float* Whf  = wts + 20960;
    float* bhf  = wts + 20992;

    // 1) zero bucket counters
    hipMemsetAsync(gcur, 0, (size_t)NBK * 4, stream);

    // 2) weight prep ∥ bucket scatter (block-specialized, self-detecting)
    prep_scatter_kernel<<<nsb + NPREP, 256, 0, stream>>>(ei, (const unsigned*)x, flags,
        gcur, pairs, Ee, Et, nsb,
        d_in[2], d_in[6], d_in[3], d_in[4], d_in[5], d_in[7], d_in[8], d_in[9],
        d_in[10], d_in[11], wts, w1x, (unsigned short*)nullptr);

    // 3) per-bucket CSR build ∥ GEMM1+attn1 (block-specialized)
    g1csr_kernel<<<NBK + (Nn + 63) / 64, 256, 0, stream>>>(pairs, gcur, rowptr, csrs, Nn,
        x, w1x, flags, h1b, as1, ad1);

    // 4) gather layer 1 + fused GEMM2 + attn2
    gather1_kernel<<<(Nn + 3) / 4, 256, 0, stream>>>(rowptr, csrs, as1, ad1,
                                                     (const unsigned*)h1b, b1f,
                                                     W2f, a2blk, h2b, as2, ad2, Nn);

    // 5) gather layer 2 + ordinal head
    gather2_kernel<<<(Nn + 3) / 4, 256, 0, stream>>>(rowptr, csrs, as2, ad2,
                                                     (const unsigned*)h2b, b2f,
                                                     Whf, bhf, flags, d_out, Nn);
}